// Round 5
// baseline (51.414 us; speedup 1.0000x reference)
//
#include <hip/hip_runtime.h>
#include <math.h>

#define HH 256
#define WW 256
#define NTHREADS 256
#define ROWSPB 4         // rows (pixels) per thread
#define MAXCHUNK 64      // LDS capacity in gaussians per staging pass
#define NSLICE 32
#define HWPIX (HH * WW)

typedef float f2 __attribute__((ext_vector_type(2)));

// round-to-nearest-even f32 -> bf16 (as uint16 in low bits)
__device__ __forceinline__ unsigned bf16rne(float f) {
    unsigned u = __float_as_uint(f);
    return (u + 0x7FFFu + ((u >> 16) & 1u)) >> 16;
}

// ---------------------------------------------------------------------------
// Partial sums. blockIdx.x = row group (4 rows x 256 cols), blockIdx.y =
// gaussian slice (32 slices -> 2048 blocks = 8 blocks/CU). Thread = column x,
// covering 4 rows. Exponent expanded per-row at staging:
//   log2(alpha) = (A*x + B)*x + E(y),  E(y) = (A*y + C)*y + D
//   A=coef, B=-2*coef*u, C=-2*coef*v, D=coef*(u^2+v^2)+log2(op)
// Invalid -> A=B=0, E=-inf (exp2 -> +0, no NaN).
// LDS record (2 x float4 = 32 B): [A,B,E0,E1][E2,E3, rg_bf16x2, bz_bf16x2]
// One record = 2 broadcast ds_read_b128 serving 4 gaussian-pixel pairs.
// ---------------------------------------------------------------------------
__global__ __launch_bounds__(NTHREADS) void partial_kernel(
    const float* __restrict__ means,
    const float* __restrict__ colors,
    const float* __restrict__ opacity,
    const float* __restrict__ scales,
    const float* __restrict__ K,
    const float* __restrict__ M,
    float* __restrict__ outp,
    int N, int nslice)
{
    __shared__ float4 sg[MAXCHUNK * 2];

    const int tid = threadIdx.x;
    const float xf  = (float)tid;
    const float y0f = (float)(blockIdx.x * ROWSPB);

    const int chunk = (N + nslice - 1) / nslice;
    const int g0 = blockIdx.y * chunk;
    const int g1 = min(N, g0 + chunk);

    float sS[ROWSPB];
    f2 aRG[ROWSPB], aBZ[ROWSPB];
    #pragma unroll
    for (int i = 0; i < ROWSPB; ++i) {
        sS[i] = 0.f;
        aRG[i] = (f2){0.f, 0.f};
        aBZ[i] = (f2){0.f, 0.f};
    }

    for (int base = g0; base < g1; base += MAXCHUNK) {
        const int cnt = min(MAXCHUNK, g1 - base);

        __syncthreads();
        if (tid < cnt) {
            const int n = base + tid;
            const float wx = means[3 * n + 0];
            const float wy = means[3 * n + 1];
            const float wz = means[3 * n + 2];
            const float px = M[0] * wx + M[1] * wy + M[2]  * wz + M[3];
            const float py = M[4] * wx + M[5] * wy + M[6]  * wz + M[7];
            const float pz = M[8] * wx + M[9] * wy + M[10] * wz + M[11];
            const float rz = 1.0f / pz;
            const float u = (K[0] * px + K[1] * py + K[2] * pz) * rz;
            const float v = (K[4] * py + K[5] * pz) * rz;
            const bool valid = (pz > 1e-4f)
                            && (u >= -(float)WW) && (u <= 2.0f * (float)WW)
                            && (v >= -(float)HH) && (v <= 2.0f * (float)HH);
            const float op  = valid ? opacity[n] : 0.0f;
            const float sig = fmaxf(scales[n] * 256.0f, 1.0f);
            const float coef = -0.72134752044448170368f / (sig * sig);

            float A, B, C, D;
            if (valid) {
                A = coef;
                B = -2.0f * coef * u;
                C = -2.0f * coef * v;
                D = fmaf(coef, fmaf(u, u, v * v), __log2f(op)); // op=0 -> -inf
            } else {
                A = 0.f; B = 0.f; C = 0.f; D = -INFINITY;
            }
            float E[ROWSPB];
            #pragma unroll
            for (int i = 0; i < ROWSPB; ++i) {
                const float yi = y0f + (float)i;
                E[i] = fmaf(fmaf(A, yi, C), yi, D);
            }
            const unsigned rg = (bf16rne(colors[3 * n + 1]) << 16) | bf16rne(colors[3 * n + 0]);
            const unsigned bz = (bf16rne(pz) << 16)               | bf16rne(colors[3 * n + 2]);
            sg[2 * tid + 0] = make_float4(A, B, E[0], E[1]);
            sg[2 * tid + 1] = make_float4(E[2], E[3],
                                          __uint_as_float(rg), __uint_as_float(bz));
        }
        __syncthreads();

        #pragma unroll 4
        for (int n = 0; n < cnt; ++n) {
            const float4 r0 = sg[2 * n + 0];
            const float4 r1 = sg[2 * n + 1];
            const unsigned rg = __float_as_uint(r1.z);
            const unsigned bz = __float_as_uint(r1.w);
            const float cr = __uint_as_float(rg << 16);
            const float cg = __uint_as_float(rg & 0xFFFF0000u);
            const float cb = __uint_as_float(bz << 16);
            const float cz = __uint_as_float(bz & 0xFFFF0000u);
            const f2 crg = {cr, cg};
            const f2 cbz = {cb, cz};
            const float q = fmaf(r0.x, xf, r0.y);    // A*x + B (shared by 4 rows)
            const float E_[ROWSPB] = {r0.z, r0.w, r1.x, r1.y};
            #pragma unroll
            for (int i = 0; i < ROWSPB; ++i) {
                const float a = fminf(exp2f(fmaf(q, xf, E_[i])), 0.95f);
                sS[i] += a;
                const f2 a2 = {a, a};
                aRG[i] = __builtin_elementwise_fma(a2, crg, aRG[i]);
                aBZ[i] = __builtin_elementwise_fma(a2, cbz, aBZ[i]);
            }
        }
    }

    float* o = outp + ((size_t)blockIdx.y * 5) * HWPIX
                    + (size_t)(blockIdx.x * ROWSPB) * WW + tid;
    #pragma unroll
    for (int i = 0; i < ROWSPB; ++i) {
        o[0 * HWPIX + i * WW] = sS[i];
        o[1 * HWPIX + i * WW] = aRG[i].x;
        o[2 * HWPIX + i * WW] = aRG[i].y;
        o[3 * HWPIX + i * WW] = aBZ[i].x;
        o[4 * HWPIX + i * WW] = aBZ[i].y;
    }
}

// ---------------------------------------------------------------------------
// Epilogue: reduce slices, normalize, composite background, clip, store.
// ---------------------------------------------------------------------------
__global__ __launch_bounds__(NTHREADS) void epilogue_kernel(
    const float* __restrict__ outp, float* __restrict__ out, int nslice)
{
    const int p = blockIdx.x * NTHREADS + threadIdx.x;
    float s = 0.f, ar = 0.f, ag = 0.f, ab = 0.f, az = 0.f;
    for (int sl = 0; sl < nslice; ++sl) {
        const float* o = outp + (size_t)(sl * 5) * HWPIX + p;
        s  += o[0 * HWPIX];
        ar += o[1 * HWPIX];
        ag += o[2 * HWPIX];
        ab += o[3 * HWPIX];
        az += o[4 * HWPIX];
    }
    const float inv   = 1.0f / (s + 1e-6f);
    const float accum = fminf(s, 1.0f);
    const float bg    = 1.0f - accum;
    out[0 * HWPIX + p] = fminf(fmaxf(fmaf(ar * inv, accum, bg), 0.0f), 1.0f);
    out[1 * HWPIX + p] = fminf(fmaxf(fmaf(ag * inv, accum, bg), 0.0f), 1.0f);
    out[2 * HWPIX + p] = fminf(fmaxf(fmaf(ab * inv, accum, bg), 0.0f), 1.0f);
    out[3 * HWPIX + p] = accum;
    out[4 * HWPIX + p] = az * inv;
}

// ---------------------------------------------------------------------------
// Fallback fused kernel (only if ws is too small) — known-good round-2 path.
// ---------------------------------------------------------------------------
__global__ __launch_bounds__(NTHREADS) void fused_kernel(
    const float* __restrict__ means,
    const float* __restrict__ colors,
    const float* __restrict__ opacity,
    const float* __restrict__ scales,
    const float* __restrict__ K,
    const float* __restrict__ M,
    float* __restrict__ out,
    int N)
{
    __shared__ float4 sg[256 * 2];
    const int tid = threadIdx.x;
    const int p   = blockIdx.x * NTHREADS + tid;
    const float x = (float)(p & (WW - 1));
    const float y = (float)(p >> 8);
    const float fx = K[0], sk = K[1], cx = K[2], fy = K[4], cy = K[5];

    float s = 0.f, ar = 0.f, ag = 0.f, ab = 0.f, az = 0.f;
    for (int base = 0; base < N; base += 256) {
        const int cnt = min(256, N - base);
        __syncthreads();
        for (int i = tid; i < cnt; i += NTHREADS) {
            const int n = base + i;
            const float wx = means[3 * n + 0];
            const float wy = means[3 * n + 1];
            const float wz = means[3 * n + 2];
            const float px = M[0] * wx + M[1] * wy + M[2]  * wz + M[3];
            const float py = M[4] * wx + M[5] * wy + M[6]  * wz + M[7];
            const float pz = M[8] * wx + M[9] * wy + M[10] * wz + M[11];
            const float rz = 1.0f / pz;
            float u = (fx * px + sk * py + cx * pz) * rz;
            float v = (fy * py + cy * pz) * rz;
            const bool valid = (pz > 1e-4f)
                            && (u >= -(float)WW) && (u <= 2.0f * (float)WW)
                            && (v >= -(float)HH) && (v <= 2.0f * (float)HH);
            const float op = valid ? opacity[n] : 0.0f;
            const float sig = fmaxf(scales[n] * 256.0f, 1.0f);
            float coef = -0.72134752044448170368f / (sig * sig);
            const float lop = __log2f(op);
            float uu = valid ? u : 0.f, vv = valid ? v : 0.f;
            float cf = valid ? coef : 0.f;
            sg[2 * i + 0] = make_float4(uu, vv, cf, lop);
            sg[2 * i + 1] = make_float4(colors[3 * n + 0], colors[3 * n + 1],
                                        colors[3 * n + 2], pz);
        }
        __syncthreads();
        for (int n = 0; n < cnt; ++n) {
            const float4 a = sg[2 * n + 0];
            const float4 c = sg[2 * n + 1];
            const float dx = x - a.x, dy = y - a.y;
            const float r2 = fmaf(dy, dy, dx * dx);
            const float alpha = fminf(exp2f(fmaf(r2, a.z, a.w)), 0.95f);
            s += alpha;
            ar = fmaf(alpha, c.x, ar); ag = fmaf(alpha, c.y, ag);
            ab = fmaf(alpha, c.z, ab); az = fmaf(alpha, c.w, az);
        }
    }
    const float inv   = 1.0f / (s + 1e-6f);
    const float accum = fminf(s, 1.0f);
    const float bg    = 1.0f - accum;
    out[0 * HWPIX + p] = fminf(fmaxf(fmaf(ar * inv, accum, bg), 0.0f), 1.0f);
    out[1 * HWPIX + p] = fminf(fmaxf(fmaf(ag * inv, accum, bg), 0.0f), 1.0f);
    out[2 * HWPIX + p] = fminf(fmaxf(fmaf(ab * inv, accum, bg), 0.0f), 1.0f);
    out[3 * HWPIX + p] = accum;
    out[4 * HWPIX + p] = az * inv;
}

extern "C" void kernel_launch(void* const* d_in, const int* in_sizes, int n_in,
                              void* d_out, int out_size, void* d_ws, size_t ws_size,
                              hipStream_t stream) {
    const float* means      = (const float*)d_in[0];
    const float* colors     = (const float*)d_in[1];
    const float* opacity    = (const float*)d_in[2];
    const float* scales     = (const float*)d_in[3];
    const float* intrinsics = (const float*)d_in[4];
    const float* w2c        = (const float*)d_in[5];
    float* out = (float*)d_out;
    float* ws  = (float*)d_ws;

    const int N = in_sizes[0] / 3;

    int nslice = NSLICE;
    while (nslice > 1 && (size_t)nslice * 5 * HWPIX * 4 > ws_size) nslice >>= 1;

    if ((size_t)5 * HWPIX * 4 > ws_size) {
        fused_kernel<<<HWPIX / NTHREADS, NTHREADS, 0, stream>>>(
            means, colors, opacity, scales, intrinsics, w2c, out, N);
        return;
    }

    dim3 grid(HH / ROWSPB, nslice);   // 64 x 32 = 2048 blocks -> 8 blocks/CU
    partial_kernel<<<grid, NTHREADS, 0, stream>>>(
        means, colors, opacity, scales, intrinsics, w2c, ws, N, nslice);
    epilogue_kernel<<<HWPIX / NTHREADS, NTHREADS, 0, stream>>>(ws, out, nslice);
}

// Round 6
// 48.072 us; speedup vs baseline: 1.0695x; 1.0695x over previous
//
#include <hip/hip_runtime.h>
#include <math.h>

#define HH 256
#define WW 256
#define NTHREADS 256
#define NSLICE 16
#define HWPIX (HH * WW)

typedef float f2 __attribute__((ext_vector_type(2)));

// round-to-nearest-even f32 -> bf16 (as uint16 in low bits)
__device__ __forceinline__ unsigned bf16rne(float f) {
    unsigned u = __float_as_uint(f);
    return (u + 0x7FFFu + ((u >> 16) & 1u)) >> 16;
}

// ---------------------------------------------------------------------------
// Partial sums. Grid (HH/2 row-pair blocks, NSLICE gaussian slices).
// Thread covers 2 pixels in one row: (row, x) and (row, x+128).
// Per 64-gaussian chunk: EVERY thread projects gaussian base+lane (each wave
// redundantly) and keeps that gaussian's bf16-packed (r,g),(b,z) in its own
// VGPRs. Wave 0 stages the exponent record [u,v,coef,lop] to LDS. Inner loop:
//   1 broadcast ds_read_b128 (exponent) + 2 readlane (colors, no LDS pipe)
//   t1 = (dx^2+dy^2)*coef + lop ; t2 = t1 + coef*(256*dx + 16384)
//   alpha = min(exp2(t), 0.95)
// Invalid/padded gaussians: u=v=coef=0, lop=-inf, z=0 -> contribute exact 0.
// ---------------------------------------------------------------------------
__global__ __launch_bounds__(NTHREADS) void partial_kernel(
    const float* __restrict__ means,
    const float* __restrict__ colors,
    const float* __restrict__ opacity,
    const float* __restrict__ scales,
    const float* __restrict__ K,
    const float* __restrict__ M,
    float* __restrict__ outp,
    int N, int nslice)
{
    __shared__ float4 sgA[64];

    const int tid  = threadIdx.x;
    const int lane = tid & 63;
    const int row  = blockIdx.x * 2 + (tid >> 7);
    const float x1 = (float)(tid & 127);
    const float yf = (float)row;

    const int chunk = (N + nslice - 1) / nslice;
    const int g0 = blockIdx.y * chunk;
    const int g1 = min(N, g0 + chunk);

    float s1 = 0.f, s2 = 0.f;
    f2 rg1 = {0.f, 0.f}, rg2 = {0.f, 0.f};
    f2 bz1 = {0.f, 0.f}, bz2 = {0.f, 0.f};

    for (int base = g0; base < g1; base += 64) {
        // ---- per-lane projection (all waves; each keeps color packs) ----
        const int  n   = base + lane;
        const bool inr = (n < g1);
        const int  nc  = inr ? n : (g1 - 1);

        const float wx = means[3 * nc + 0];
        const float wy = means[3 * nc + 1];
        const float wz = means[3 * nc + 2];
        const float px = M[0] * wx + M[1] * wy + M[2]  * wz + M[3];
        const float py = M[4] * wx + M[5] * wy + M[6]  * wz + M[7];
        const float pz = M[8] * wx + M[9] * wy + M[10] * wz + M[11];
        const float rz = 1.0f / pz;
        const float u  = (K[0] * px + K[1] * py + K[2] * pz) * rz;
        const float v  = (K[4] * py + K[5] * pz) * rz;
        const bool valid = inr && (pz > 1e-4f)
                        && (u >= -(float)WW) && (u <= 2.0f * (float)WW)
                        && (v >= -(float)HH) && (v <= 2.0f * (float)HH);
        const float op  = valid ? opacity[nc] : 0.0f;
        const float sig = fmaxf(scales[nc] * 256.0f, 1.0f);
        const float cf0 = -0.72134752044448170368f / (sig * sig); // -0.5*log2e/sig^2

        float U, V, CF, LP;
        if (valid) { U = u; V = v; CF = cf0; LP = __log2f(op); }
        else       { U = 0.f; V = 0.f; CF = 0.f; LP = -INFINITY; }
        const float zz = valid ? pz : 0.0f;

        const unsigned crg = (bf16rne(colors[3 * nc + 1]) << 16)
                           |  bf16rne(colors[3 * nc + 0]);
        const unsigned cbz = (bf16rne(zz) << 16)
                           |  bf16rne(colors[3 * nc + 2]);

        if (tid < 64) sgA[tid] = make_float4(U, V, CF, LP);
        __syncthreads();

        // ---- inner: 64 gaussians (padded entries contribute exact 0) ----
        #pragma unroll 16
        for (int k = 0; k < 64; ++k) {
            const float4   a   = sgA[k];
            const unsigned prg = __builtin_amdgcn_readlane(crg, k);
            const unsigned pbz = __builtin_amdgcn_readlane(cbz, k);
            const float dx  = x1 - a.x;
            const float dy  = yf - a.y;
            const float r2a = fmaf(dx, dx, dy * dy);
            const float ta  = fmaf(r2a, a.z, a.w);
            const float dl  = fmaf(dx, 256.0f, 16384.0f);  // (dx+128)^2 - dx^2
            const float tb  = fmaf(dl, a.z, ta);
            const float ea  = fminf(exp2f(ta), 0.95f);
            const float eb  = fminf(exp2f(tb), 0.95f);
            const f2 c0 = { __uint_as_float(prg << 16),
                            __uint_as_float(prg & 0xFFFF0000u) };  // (r, g)
            const f2 c1 = { __uint_as_float(pbz << 16),
                            __uint_as_float(pbz & 0xFFFF0000u) };  // (b, z)
            s1 += ea;  s2 += eb;
            rg1 = __builtin_elementwise_fma((f2){ea, ea}, c0, rg1);
            bz1 = __builtin_elementwise_fma((f2){ea, ea}, c1, bz1);
            rg2 = __builtin_elementwise_fma((f2){eb, eb}, c0, rg2);
            bz2 = __builtin_elementwise_fma((f2){eb, eb}, c1, bz2);
        }
        __syncthreads();
    }

    float* o = outp + ((size_t)blockIdx.y * 5) * HWPIX
                    + (size_t)row * WW + (tid & 127);
    o[0 * HWPIX] = s1;      o[0 * HWPIX + 128] = s2;
    o[1 * HWPIX] = rg1.x;   o[1 * HWPIX + 128] = rg2.x;
    o[2 * HWPIX] = rg1.y;   o[2 * HWPIX + 128] = rg2.y;
    o[3 * HWPIX] = bz1.x;   o[3 * HWPIX + 128] = bz2.x;
    o[4 * HWPIX] = bz1.y;   o[4 * HWPIX + 128] = bz2.y;
}

// ---------------------------------------------------------------------------
// Epilogue: reduce slices, normalize, composite background, clip, store.
// ---------------------------------------------------------------------------
__global__ __launch_bounds__(NTHREADS) void epilogue_kernel(
    const float* __restrict__ outp, float* __restrict__ out, int nslice)
{
    const int p = blockIdx.x * NTHREADS + threadIdx.x;
    float s = 0.f, ar = 0.f, ag = 0.f, ab = 0.f, az = 0.f;
    for (int sl = 0; sl < nslice; ++sl) {
        const float* o = outp + (size_t)(sl * 5) * HWPIX + p;
        s  += o[0 * HWPIX];
        ar += o[1 * HWPIX];
        ag += o[2 * HWPIX];
        ab += o[3 * HWPIX];
        az += o[4 * HWPIX];
    }
    const float inv   = 1.0f / (s + 1e-6f);
    const float accum = fminf(s, 1.0f);
    const float bg    = 1.0f - accum;
    out[0 * HWPIX + p] = fminf(fmaxf(fmaf(ar * inv, accum, bg), 0.0f), 1.0f);
    out[1 * HWPIX + p] = fminf(fmaxf(fmaf(ag * inv, accum, bg), 0.0f), 1.0f);
    out[2 * HWPIX + p] = fminf(fmaxf(fmaf(ab * inv, accum, bg), 0.0f), 1.0f);
    out[3 * HWPIX + p] = accum;
    out[4 * HWPIX + p] = az * inv;
}

// ---------------------------------------------------------------------------
// Fallback fused kernel (only if ws is too small) — known-good round-2 path.
// ---------------------------------------------------------------------------
__global__ __launch_bounds__(NTHREADS) void fused_kernel(
    const float* __restrict__ means,
    const float* __restrict__ colors,
    const float* __restrict__ opacity,
    const float* __restrict__ scales,
    const float* __restrict__ K,
    const float* __restrict__ M,
    float* __restrict__ out,
    int N)
{
    __shared__ float4 sg[256 * 2];
    const int tid = threadIdx.x;
    const int p   = blockIdx.x * NTHREADS + tid;
    const float x = (float)(p & (WW - 1));
    const float y = (float)(p >> 8);
    const float fx = K[0], sk = K[1], cx = K[2], fy = K[4], cy = K[5];

    float s = 0.f, ar = 0.f, ag = 0.f, ab = 0.f, az = 0.f;
    for (int base = 0; base < N; base += 256) {
        const int cnt = min(256, N - base);
        __syncthreads();
        for (int i = tid; i < cnt; i += NTHREADS) {
            const int n = base + i;
            const float wx = means[3 * n + 0];
            const float wy = means[3 * n + 1];
            const float wz = means[3 * n + 2];
            const float px = M[0] * wx + M[1] * wy + M[2]  * wz + M[3];
            const float py = M[4] * wx + M[5] * wy + M[6]  * wz + M[7];
            const float pz = M[8] * wx + M[9] * wy + M[10] * wz + M[11];
            const float rz = 1.0f / pz;
            float u = (fx * px + sk * py + cx * pz) * rz;
            float v = (fy * py + cy * pz) * rz;
            const bool valid = (pz > 1e-4f)
                            && (u >= -(float)WW) && (u <= 2.0f * (float)WW)
                            && (v >= -(float)HH) && (v <= 2.0f * (float)HH);
            const float op = valid ? opacity[n] : 0.0f;
            const float sig = fmaxf(scales[n] * 256.0f, 1.0f);
            float coef = -0.72134752044448170368f / (sig * sig);
            const float lop = __log2f(op);
            float uu = valid ? u : 0.f, vv = valid ? v : 0.f;
            float cf = valid ? coef : 0.f;
            sg[2 * i + 0] = make_float4(uu, vv, cf, lop);
            sg[2 * i + 1] = make_float4(colors[3 * n + 0], colors[3 * n + 1],
                                        colors[3 * n + 2], pz);
        }
        __syncthreads();
        for (int n = 0; n < cnt; ++n) {
            const float4 a = sg[2 * n + 0];
            const float4 c = sg[2 * n + 1];
            const float dx = x - a.x, dy = y - a.y;
            const float r2 = fmaf(dy, dy, dx * dx);
            const float alpha = fminf(exp2f(fmaf(r2, a.z, a.w)), 0.95f);
            s += alpha;
            ar = fmaf(alpha, c.x, ar); ag = fmaf(alpha, c.y, ag);
            ab = fmaf(alpha, c.z, ab); az = fmaf(alpha, c.w, az);
        }
    }
    const float inv   = 1.0f / (s + 1e-6f);
    const float accum = fminf(s, 1.0f);
    const float bg    = 1.0f - accum;
    out[0 * HWPIX + p] = fminf(fmaxf(fmaf(ar * inv, accum, bg), 0.0f), 1.0f);
    out[1 * HWPIX + p] = fminf(fmaxf(fmaf(ag * inv, accum, bg), 0.0f), 1.0f);
    out[2 * HWPIX + p] = fminf(fmaxf(fmaf(ab * inv, accum, bg), 0.0f), 1.0f);
    out[3 * HWPIX + p] = accum;
    out[4 * HWPIX + p] = az * inv;
}

extern "C" void kernel_launch(void* const* d_in, const int* in_sizes, int n_in,
                              void* d_out, int out_size, void* d_ws, size_t ws_size,
                              hipStream_t stream) {
    const float* means      = (const float*)d_in[0];
    const float* colors     = (const float*)d_in[1];
    const float* opacity    = (const float*)d_in[2];
    const float* scales     = (const float*)d_in[3];
    const float* intrinsics = (const float*)d_in[4];
    const float* w2c        = (const float*)d_in[5];
    float* out = (float*)d_out;
    float* ws  = (float*)d_ws;

    const int N = in_sizes[0] / 3;

    int nslice = NSLICE;
    while (nslice > 1 && (size_t)nslice * 5 * HWPIX * 4 > ws_size) nslice >>= 1;

    if ((size_t)5 * HWPIX * 4 > ws_size) {
        fused_kernel<<<HWPIX / NTHREADS, NTHREADS, 0, stream>>>(
            means, colors, opacity, scales, intrinsics, w2c, out, N);
        return;
    }

    dim3 grid(HH / 2, nslice);   // 128 x 16 = 2048 blocks -> 8 blocks/CU
    partial_kernel<<<grid, NTHREADS, 0, stream>>>(
        means, colors, opacity, scales, intrinsics, w2c, ws, N, nslice);
    epilogue_kernel<<<HWPIX / NTHREADS, NTHREADS, 0, stream>>>(ws, out, nslice);
}

// Round 7
// 31.000 us; speedup vs baseline: 1.6585x; 1.5507x over previous
//
#include <hip/hip_runtime.h>
#include <math.h>

#define HH 256
#define WW 256
#define NTHREADS 256
#define CHUNKG 128            // gaussians per block (one slice)
#define HWPIX (HH * WW)

typedef short s8v __attribute__((ext_vector_type(8)));   // 8 bf16 (4 VGPRs)
typedef float f4v __attribute__((ext_vector_type(4)));   // MFMA accumulator

// pack two f32 as bf16 (truncate) into one u32: lo=first, hi=second
__device__ __forceinline__ unsigned pk_trunc(float lo, float hi) {
    return (__float_as_uint(hi) & 0xFFFF0000u) | (__float_as_uint(lo) >> 16);
}

// ---------------------------------------------------------------------------
// MFMA partial kernel. Block = one image row (y = blockIdx.x) x one slice of
// 128 gaussians (blockIdx.y). 4 waves, each owning 64 consecutive x.
// Exponent per gaussian expanded at staging for this row:
//   log2(alpha) = A*x^2 + B*x + E,  E = (A*y + C)*y + D
//   A=coef, B=-2*coef*u, C=-2*coef*v, D=coef*(u^2+v^2)+log2(op)
// GEMM via mfma_f32_16x16x32_bf16: A-frag = alpha (16 px x 32 g, bf16),
// B-frag = payload C[g][c], c in {1, r, g, b, z} (cols 5..15 zero).
// Both A and B use k = (lane>>4)*8 + j per-lane enumeration (consistent ->
// immune to within-lane k permutation). D: col=lane&15, row=(lane>>4)*4+reg.
// ---------------------------------------------------------------------------
__global__ __launch_bounds__(NTHREADS, 6) void partial_kernel(
    const float* __restrict__ means,
    const float* __restrict__ colors,
    const float* __restrict__ opacity,
    const float* __restrict__ scales,
    const float* __restrict__ K,
    const float* __restrict__ M,
    float* __restrict__ outp,
    int N)
{
    __shared__ float4   prm[CHUNKG];            // {A, B, E, 0}
    __shared__ float4   colf[CHUNKG];           // {r, g, b, z}
    __shared__ unsigned bfr[(CHUNKG / 32) * 256];  // B-frags, u32 per (chunk,lane,reg)

    const int tid = threadIdx.x;
    const int y   = blockIdx.x;
    const int g0  = blockIdx.y * CHUNKG;
    const float yf = (float)y;

    // ---- Phase 1: project this slice's gaussians (threads 0..127) ----
    if (tid < CHUNKG) {
        const int n = g0 + tid;
        float A = 0.f, Bc = 0.f, E = -INFINITY;
        float4 cf = make_float4(0.f, 0.f, 0.f, 0.f);
        if (n < N) {
            const float wx = means[3 * n + 0];
            const float wy = means[3 * n + 1];
            const float wz = means[3 * n + 2];
            const float px = M[0] * wx + M[1] * wy + M[2]  * wz + M[3];
            const float py = M[4] * wx + M[5] * wy + M[6]  * wz + M[7];
            const float pz = M[8] * wx + M[9] * wy + M[10] * wz + M[11];
            const float rz = 1.0f / pz;
            const float u  = (K[0] * px + K[1] * py + K[2] * pz) * rz;
            const float v  = (K[4] * py + K[5] * pz) * rz;
            const bool valid = (pz > 1e-4f)
                            && (u >= -(float)WW) && (u <= 2.0f * (float)WW)
                            && (v >= -(float)HH) && (v <= 2.0f * (float)HH);
            if (valid) {
                const float op  = opacity[n];
                const float sig = fmaxf(scales[n] * 256.0f, 1.0f);
                const float coef = -0.72134752044448170368f / (sig * sig); // -0.5*log2e/sig^2
                A  = coef;
                Bc = -2.0f * coef * u;
                const float C = -2.0f * coef * v;
                const float D = fmaf(coef, fmaf(u, u, v * v), __log2f(op)); // op=0 -> -inf
                E  = fmaf(fmaf(A, yf, C), yf, D);
                cf = make_float4(colors[3 * n + 0], colors[3 * n + 1],
                                 colors[3 * n + 2], pz);
            }
        }
        prm[tid]  = make_float4(A, Bc, E, 0.f);
        colf[tid] = cf;
    }
    __syncthreads();

    // ---- Phase 2: build B-fragments (payload matrix in MFMA B layout) ----
    for (int e = tid; e < (CHUNKG / 32) * 256; e += NTHREADS) {
        const int lane6 = (e >> 2) & 63;
        const int reg   = e & 3;
        const int kl    = ((e >> 8) << 5) + ((lane6 >> 4) << 3) + (reg << 1);
        const int col   = lane6 & 15;
        const float4 c0 = colf[kl];
        const float4 c1 = colf[kl + 1];
        const float lo = (col == 0) ? 1.f : (col == 1) ? c0.x : (col == 2) ? c0.y
                       : (col == 3) ? c0.z : (col == 4) ? c0.w : 0.f;
        const float hi = (col == 0) ? 1.f : (col == 1) ? c1.x : (col == 2) ? c1.y
                       : (col == 3) ? c1.z : (col == 4) ? c1.w : 0.f;
        bfr[e] = pk_trunc(lo, hi);
    }
    __syncthreads();

    // ---- Phase 3: alpha eval + MFMA accumulate ----
    const int lane = tid & 63;
    const int wv   = tid >> 6;          // wave covers x in [wv*64, wv*64+64)
    const int kq   = (lane >> 4) << 3;  // this lane's k-block base (0,8,16,24)

    f4v acc[4];
    #pragma unroll
    for (int t = 0; t < 4; ++t) acc[t] = (f4v){0.f, 0.f, 0.f, 0.f};

    float xs[4], xxs[4];
    #pragma unroll
    for (int t = 0; t < 4; ++t) {
        xs[t]  = (float)(wv * 64 + t * 16 + (lane & 15));
        xxs[t] = xs[t] * xs[t];
    }

    #pragma unroll
    for (int c = 0; c < CHUNKG / 32; ++c) {
        float4 P[8];
        #pragma unroll
        for (int j = 0; j < 8; ++j) P[j] = prm[c * 32 + kq + j];

        union { s8v v; uint4 q; } Bf;
        Bf.q = *(const uint4*)&bfr[c * 256 + lane * 4];

        #pragma unroll
        for (int t = 0; t < 4; ++t) {
            union { s8v v; unsigned u[4]; } Af;
            #pragma unroll
            for (int r = 0; r < 4; ++r) {
                const float4 p0 = P[2 * r];
                const float4 p1 = P[2 * r + 1];
                const float a0 = fminf(exp2f(fmaf(p0.y, xs[t], fmaf(p0.x, xxs[t], p0.z))), 0.95f);
                const float a1 = fminf(exp2f(fmaf(p1.y, xs[t], fmaf(p1.x, xxs[t], p1.z))), 0.95f);
                Af.u[r] = pk_trunc(a0, a1);
            }
            acc[t] = __builtin_amdgcn_mfma_f32_16x16x32_bf16(Af.v, Bf.v, acc[t], 0, 0, 0);
        }
    }

    // ---- Store: lane holds payload col=lane&15 for rows (lane>>4)*4+r ----
    const int col = lane & 15;
    if (col < 5) {
        float* pl = outp + ((size_t)blockIdx.y * 5 + col) * HWPIX + (size_t)y * WW;
        const int rb = (lane >> 4) << 2;
        #pragma unroll
        for (int t = 0; t < 4; ++t) {
            #pragma unroll
            for (int r = 0; r < 4; ++r) {
                pl[wv * 64 + t * 16 + rb + r] = acc[t][r];
            }
        }
    }
}

// ---------------------------------------------------------------------------
// Epilogue: reduce slices, normalize, composite background, clip, store.
// Partials layout: [slice][payload(S,r,g,b,z)][pixel]
// ---------------------------------------------------------------------------
__global__ __launch_bounds__(NTHREADS) void epilogue_kernel(
    const float* __restrict__ outp, float* __restrict__ out, int nslice)
{
    const int p = blockIdx.x * NTHREADS + threadIdx.x;
    float s = 0.f, ar = 0.f, ag = 0.f, ab = 0.f, az = 0.f;
    for (int sl = 0; sl < nslice; ++sl) {
        const float* o = outp + (size_t)(sl * 5) * HWPIX + p;
        s  += o[0 * HWPIX];
        ar += o[1 * HWPIX];
        ag += o[2 * HWPIX];
        ab += o[3 * HWPIX];
        az += o[4 * HWPIX];
    }
    const float inv   = 1.0f / (s + 1e-6f);
    const float accum = fminf(s, 1.0f);
    const float bg    = 1.0f - accum;
    out[0 * HWPIX + p] = fminf(fmaxf(fmaf(ar * inv, accum, bg), 0.0f), 1.0f);
    out[1 * HWPIX + p] = fminf(fmaxf(fmaf(ag * inv, accum, bg), 0.0f), 1.0f);
    out[2 * HWPIX + p] = fminf(fmaxf(fmaf(ab * inv, accum, bg), 0.0f), 1.0f);
    out[3 * HWPIX + p] = accum;
    out[4 * HWPIX + p] = az * inv;
}

// ---------------------------------------------------------------------------
// Fallback fused kernel (only if ws is too small) — known-good round-2 path.
// ---------------------------------------------------------------------------
__global__ __launch_bounds__(NTHREADS) void fused_kernel(
    const float* __restrict__ means,
    const float* __restrict__ colors,
    const float* __restrict__ opacity,
    const float* __restrict__ scales,
    const float* __restrict__ K,
    const float* __restrict__ M,
    float* __restrict__ out,
    int N)
{
    __shared__ float4 sg[256 * 2];
    const int tid = threadIdx.x;
    const int p   = blockIdx.x * NTHREADS + tid;
    const float x = (float)(p & (WW - 1));
    const float y = (float)(p >> 8);
    const float fx = K[0], sk = K[1], cx = K[2], fy = K[4], cy = K[5];

    float s = 0.f, ar = 0.f, ag = 0.f, ab = 0.f, az = 0.f;
    for (int base = 0; base < N; base += 256) {
        const int cnt = min(256, N - base);
        __syncthreads();
        for (int i = tid; i < cnt; i += NTHREADS) {
            const int n = base + i;
            const float wx = means[3 * n + 0];
            const float wy = means[3 * n + 1];
            const float wz = means[3 * n + 2];
            const float px = M[0] * wx + M[1] * wy + M[2]  * wz + M[3];
            const float py = M[4] * wx + M[5] * wy + M[6]  * wz + M[7];
            const float pz = M[8] * wx + M[9] * wy + M[10] * wz + M[11];
            const float rz = 1.0f / pz;
            float u = (fx * px + sk * py + cx * pz) * rz;
            float v = (fy * py + cy * pz) * rz;
            const bool valid = (pz > 1e-4f)
                            && (u >= -(float)WW) && (u <= 2.0f * (float)WW)
                            && (v >= -(float)HH) && (v <= 2.0f * (float)HH);
            const float op = valid ? opacity[n] : 0.0f;
            const float sig = fmaxf(scales[n] * 256.0f, 1.0f);
            float coef = -0.72134752044448170368f / (sig * sig);
            const float lop = __log2f(op);
            float uu = valid ? u : 0.f, vv = valid ? v : 0.f;
            float cf = valid ? coef : 0.f;
            sg[2 * i + 0] = make_float4(uu, vv, cf, lop);
            sg[2 * i + 1] = make_float4(colors[3 * n + 0], colors[3 * n + 1],
                                        colors[3 * n + 2], pz);
        }
        __syncthreads();
        for (int n = 0; n < cnt; ++n) {
            const float4 a = sg[2 * n + 0];
            const float4 c = sg[2 * n + 1];
            const float dx = x - a.x, dy = y - a.y;
            const float r2 = fmaf(dy, dy, dx * dx);
            const float alpha = fminf(exp2f(fmaf(r2, a.z, a.w)), 0.95f);
            s += alpha;
            ar = fmaf(alpha, c.x, ar); ag = fmaf(alpha, c.y, ag);
            ab = fmaf(alpha, c.z, ab); az = fmaf(alpha, c.w, az);
        }
    }
    const float inv   = 1.0f / (s + 1e-6f);
    const float accum = fminf(s, 1.0f);
    const float bg    = 1.0f - accum;
    out[0 * HWPIX + p] = fminf(fmaxf(fmaf(ar * inv, accum, bg), 0.0f), 1.0f);
    out[1 * HWPIX + p] = fminf(fmaxf(fmaf(ag * inv, accum, bg), 0.0f), 1.0f);
    out[2 * HWPIX + p] = fminf(fmaxf(fmaf(ab * inv, accum, bg), 0.0f), 1.0f);
    out[3 * HWPIX + p] = accum;
    out[4 * HWPIX + p] = az * inv;
}

extern "C" void kernel_launch(void* const* d_in, const int* in_sizes, int n_in,
                              void* d_out, int out_size, void* d_ws, size_t ws_size,
                              hipStream_t stream) {
    const float* means      = (const float*)d_in[0];
    const float* colors     = (const float*)d_in[1];
    const float* opacity    = (const float*)d_in[2];
    const float* scales     = (const float*)d_in[3];
    const float* intrinsics = (const float*)d_in[4];
    const float* w2c        = (const float*)d_in[5];
    float* out = (float*)d_out;
    float* ws  = (float*)d_ws;

    const int N = in_sizes[0] / 3;
    const int nslice = (N + CHUNKG - 1) / CHUNKG;   // 8 for N=1024

    if ((size_t)nslice * 5 * HWPIX * 4 > ws_size) {
        fused_kernel<<<HWPIX / NTHREADS, NTHREADS, 0, stream>>>(
            means, colors, opacity, scales, intrinsics, w2c, out, N);
        return;
    }

    dim3 grid(HH, nslice);   // 256 rows x 8 slices = 2048 blocks -> 8/CU
    partial_kernel<<<grid, NTHREADS, 0, stream>>>(
        means, colors, opacity, scales, intrinsics, w2c, ws, N);
    epilogue_kernel<<<HWPIX / NTHREADS, NTHREADS, 0, stream>>>(ws, out, nslice);
}